// Round 2
// baseline (8457.343 us; speedup 1.0000x reference)
//
#include <hip/hip_runtime.h>

#define N_NODES  100000
#define N_EDGES  1600000
#define NODE_DIM 64
#define HID      32
#define NUM_LAYERS 3

// ---------------------------------------------------------------------------
// Generic 2-layer MLP on a per-thread input vector held in registers.
// Weight/bias addresses depend only on loop counters + kernel args -> wave-
// uniform -> compiler emits scalar (s_load) loads; FMAs are v_fmac v,s,v.
// ---------------------------------------------------------------------------
template <int IN>
__device__ __forceinline__ void mlp2(const float (&in)[IN],
                                     const float* __restrict__ w1,
                                     const float* __restrict__ b1,
                                     const float* __restrict__ w2,
                                     const float* __restrict__ b2,
                                     float (&out)[HID]) {
    float h[HID];
#pragma unroll
    for (int j = 0; j < HID; ++j) h[j] = b1[j];
    for (int k = 0; k < IN; ++k) {
        float v = in[k];
#pragma unroll
        for (int j = 0; j < HID; ++j) h[j] = fmaf(v, w1[k * HID + j], h[j]);
    }
#pragma unroll
    for (int j = 0; j < HID; ++j) h[j] = fmaxf(h[j], 0.0f);
#pragma unroll
    for (int j = 0; j < HID; ++j) out[j] = b2[j];
    for (int k = 0; k < HID; ++k) {
        float v = h[k];
#pragma unroll
        for (int j = 0; j < HID; ++j) out[j] = fmaf(v, w2[k * HID + j], out[j]);
    }
}

__device__ __forceinline__ void load_row32(const float* __restrict__ p, float* dst) {
    const float4* p4 = reinterpret_cast<const float4*>(p);
#pragma unroll
    for (int k = 0; k < HID / 4; ++k) {
        float4 v = p4[k];
        dst[4 * k + 0] = v.x; dst[4 * k + 1] = v.y;
        dst[4 * k + 2] = v.z; dst[4 * k + 3] = v.w;
    }
}

__device__ __forceinline__ void store_row32(float* __restrict__ p, const float* src) {
    float4* p4 = reinterpret_cast<float4*>(p);
#pragma unroll
    for (int k = 0; k < HID / 4; ++k) {
        float4 v;
        v.x = src[4 * k + 0]; v.y = src[4 * k + 1];
        v.z = src[4 * k + 2]; v.w = src[4 * k + 3];
        p4[k] = v;
    }
}

// ---------------------------------------------------------------------------
__global__ void zero_kernel(float* __restrict__ p, int n4) {
    int i = blockIdx.x * blockDim.x + threadIdx.x;
    if (i < n4) reinterpret_cast<float4*>(p)[i] = make_float4(0.f, 0.f, 0.f, 0.f);
}

__global__ void dist_kernel(const int* __restrict__ ei,
                            const float* __restrict__ pos,
                            float* __restrict__ dist) {
    int e = blockIdx.x * blockDim.x + threadIdx.x;
    if (e >= N_EDGES) return;
    int s = ei[e];
    int d = ei[N_EDGES + e];
    float dx = pos[d * 3 + 0] - pos[s * 3 + 0];
    float dy = pos[d * 3 + 1] - pos[s * 3 + 1];
    float dz = pos[d * 3 + 2] - pos[s * 3 + 2];
    dist[e] = sqrtf(dx * dx + dy * dy + dz * dz);
}

__global__ void encoder_kernel(const float* __restrict__ feat,
                               const float* __restrict__ w1, const float* __restrict__ b1,
                               const float* __restrict__ w2, const float* __restrict__ b2,
                               float* __restrict__ xout) {
    int n = blockIdx.x * blockDim.x + threadIdx.x;
    if (n >= N_NODES) return;
    float f[NODE_DIM];
    const float4* fp = reinterpret_cast<const float4*>(feat + (size_t)n * NODE_DIM);
#pragma unroll
    for (int k = 0; k < NODE_DIM / 4; ++k) {
        float4 v = fp[k];
        f[4 * k + 0] = v.x; f[4 * k + 1] = v.y;
        f[4 * k + 2] = v.z; f[4 * k + 3] = v.w;
    }
    float y[HID];
    mlp2<NODE_DIM>(f, w1, b1, w2, b2, y);
    store_row32(xout + (size_t)n * HID, y);
}

__global__ void msg_kernel(const int* __restrict__ ei,
                           const float* __restrict__ x,
                           const float* __restrict__ dist,
                           const float* __restrict__ w1, const float* __restrict__ b1,
                           const float* __restrict__ w2, const float* __restrict__ b2,
                           float* __restrict__ agg) {
    int e = blockIdx.x * blockDim.x + threadIdx.x;
    if (e >= N_EDGES) return;
    int s = ei[e];
    int d = ei[N_EDGES + e];

    float in[2 * HID + 1];
    load_row32(x + (size_t)d * HID, in);          // x_i = x[dst]
    load_row32(x + (size_t)s * HID, in + HID);    // x_j = x[src]
    in[2 * HID] = dist[e];

    float m[HID];
    mlp2<2 * HID + 1>(in, w1, b1, w2, b2, m);

    float* aggp = agg + (size_t)d * HID;
#pragma unroll
    for (int j = 0; j < HID; ++j) atomicAdd(&aggp[j], m[j]);
}

// In-place: thread n reads only row n of x/agg, writes row n of x.
__global__ void update_kernel(float* __restrict__ x,
                              const float* __restrict__ agg,
                              const float* __restrict__ w1, const float* __restrict__ b1,
                              const float* __restrict__ w2, const float* __restrict__ b2) {
    int n = blockIdx.x * blockDim.x + threadIdx.x;
    if (n >= N_NODES) return;
    float in[2 * HID];
    load_row32(x + (size_t)n * HID, in);
    load_row32(agg + (size_t)n * HID, in + HID);
    float y[HID];
    mlp2<2 * HID>(in, w1, b1, w2, b2, y);
    store_row32(x + (size_t)n * HID, y);
}

__global__ void out_kernel(const float* __restrict__ x,
                           const float* __restrict__ w, const float* __restrict__ b,
                           float* __restrict__ out) {
    int n = blockIdx.x * blockDim.x + threadIdx.x;
    if (n >= N_NODES) return;
    float in[HID];
    load_row32(x + (size_t)n * HID, in);
    float y[HID];
#pragma unroll
    for (int j = 0; j < HID; ++j) y[j] = b[j];
    for (int k = 0; k < HID; ++k) {
        float v = in[k];
#pragma unroll
        for (int j = 0; j < HID; ++j) y[j] = fmaf(v, w[k * HID + j], y[j]);
    }
    store_row32(out + (size_t)n * HID, y);
}

// ---------------------------------------------------------------------------
extern "C" void kernel_launch(void* const* d_in, const int* in_sizes, int n_in,
                              void* d_out, int out_size, void* d_ws, size_t ws_size,
                              hipStream_t stream) {
    const float* node_feat = (const float*)d_in[0];
    const float* pos       = (const float*)d_in[1];
    const int*   ei        = (const int*)  d_in[2];   // harness gives int32
    const float* enc_w1    = (const float*)d_in[3];
    const float* enc_b1    = (const float*)d_in[4];
    const float* enc_w2    = (const float*)d_in[5];
    const float* enc_b2    = (const float*)d_in[6];
    const float* msg_w1    = (const float*)d_in[7];   // [3, 65, 32]
    const float* msg_b1    = (const float*)d_in[8];   // [3, 32]
    const float* msg_w2    = (const float*)d_in[9];   // [3, 32, 32]
    const float* msg_b2    = (const float*)d_in[10];
    const float* upd_w1    = (const float*)d_in[11];  // [3, 64, 32]
    const float* upd_b1    = (const float*)d_in[12];
    const float* upd_w2    = (const float*)d_in[13];
    const float* upd_b2    = (const float*)d_in[14];
    const float* out_w     = (const float*)d_in[15];
    const float* out_b     = (const float*)d_in[16];
    float* out = (float*)d_out;

    // workspace layout (floats): dist[E] | x[N*32] | agg[N*32]  = 32 MB
    float* ws   = (float*)d_ws;
    float* dist = ws;
    float* x    = ws + (size_t)N_EDGES;
    float* agg  = x + (size_t)N_NODES * HID;

    const int B = 256;
    const int gridE = (N_EDGES + B - 1) / B;
    const int gridN = (N_NODES + B - 1) / B;
    const int aggN4 = N_NODES * HID / 4;
    const int gridZ = (aggN4 + B - 1) / B;

    dist_kernel<<<gridE, B, 0, stream>>>(ei, pos, dist);
    encoder_kernel<<<gridN, B, 0, stream>>>(node_feat, enc_w1, enc_b1, enc_w2, enc_b2, x);

    for (int l = 0; l < NUM_LAYERS; ++l) {
        zero_kernel<<<gridZ, B, 0, stream>>>(agg, aggN4);
        msg_kernel<<<gridE, B, 0, stream>>>(ei, x, dist,
                                            msg_w1 + (size_t)l * (2 * HID + 1) * HID,
                                            msg_b1 + (size_t)l * HID,
                                            msg_w2 + (size_t)l * HID * HID,
                                            msg_b2 + (size_t)l * HID,
                                            agg);
        update_kernel<<<gridN, B, 0, stream>>>(x, agg,
                                               upd_w1 + (size_t)l * (2 * HID) * HID,
                                               upd_b1 + (size_t)l * HID,
                                               upd_w2 + (size_t)l * HID * HID,
                                               upd_b2 + (size_t)l * HID);
    }
    out_kernel<<<gridN, B, 0, stream>>>(x, out_w, out_b, out);
}

// Round 3
// 557.700 us; speedup vs baseline: 15.1647x; 15.1647x over previous
//
#include <hip/hip_runtime.h>

#define N_NODES  100000
#define N_EDGES  1600000
#define NODE_DIM 64
#define HID      32
#define NUM_LAYERS 3
#define SCAN_B   1024   // elements per scan1 block

// ---------------------------------------------------------------------------
template <int IN>
__device__ __forceinline__ void mlp2(const float (&in)[IN],
                                     const float* __restrict__ w1,
                                     const float* __restrict__ b1,
                                     const float* __restrict__ w2,
                                     const float* __restrict__ b2,
                                     float (&out)[HID]) {
    float h[HID];
#pragma unroll
    for (int j = 0; j < HID; ++j) h[j] = b1[j];
    for (int k = 0; k < IN; ++k) {
        float v = in[k];
#pragma unroll
        for (int j = 0; j < HID; ++j) h[j] = fmaf(v, w1[k * HID + j], h[j]);
    }
#pragma unroll
    for (int j = 0; j < HID; ++j) h[j] = fmaxf(h[j], 0.0f);
#pragma unroll
    for (int j = 0; j < HID; ++j) out[j] = b2[j];
    for (int k = 0; k < HID; ++k) {
        float v = h[k];
#pragma unroll
        for (int j = 0; j < HID; ++j) out[j] = fmaf(v, w2[k * HID + j], out[j]);
    }
}

__device__ __forceinline__ void load_row32(const float* __restrict__ p, float* dst) {
    const float4* p4 = reinterpret_cast<const float4*>(p);
#pragma unroll
    for (int k = 0; k < HID / 4; ++k) {
        float4 v = p4[k];
        dst[4 * k + 0] = v.x; dst[4 * k + 1] = v.y;
        dst[4 * k + 2] = v.z; dst[4 * k + 3] = v.w;
    }
}

__device__ __forceinline__ void store_row32(float* __restrict__ p, const float* src) {
    float4* p4 = reinterpret_cast<float4*>(p);
#pragma unroll
    for (int k = 0; k < HID / 4; ++k) {
        float4 v;
        v.x = src[4 * k + 0]; v.y = src[4 * k + 1];
        v.z = src[4 * k + 2]; v.w = src[4 * k + 3];
        p4[k] = v;
    }
}

// ------------------------------- sort: CSR by dst ---------------------------
__global__ void zero_int_kernel(int* __restrict__ p, int n) {
    int i = blockIdx.x * blockDim.x + threadIdx.x;
    if (i < n) p[i] = 0;
}

__global__ void rank_kernel(const int* __restrict__ ei,
                            int* __restrict__ cnt, int* __restrict__ rank) {
    int e = blockIdx.x * blockDim.x + threadIdx.x;
    if (e >= N_EDGES) return;
    int d = ei[N_EDGES + e];
    rank[e] = atomicAdd(&cnt[d], 1);
}

// scan1: per-block exclusive scan of cnt (1024 elems/block of 256 threads)
__global__ void scan1_kernel(const int* __restrict__ cnt, int* __restrict__ off,
                             int* __restrict__ bsum) {
    __shared__ int lds[256];
    int tid = threadIdx.x;
    int base = blockIdx.x * SCAN_B + tid * 4;
    int v0 = (base + 0 < N_NODES) ? cnt[base + 0] : 0;
    int v1 = (base + 1 < N_NODES) ? cnt[base + 1] : 0;
    int v2 = (base + 2 < N_NODES) ? cnt[base + 2] : 0;
    int v3 = (base + 3 < N_NODES) ? cnt[base + 3] : 0;
    int s1 = v0, s2 = v0 + v1, s3 = v0 + v1 + v2;
    int tsum = s3 + v3;
    lds[tid] = tsum;
    __syncthreads();
    for (int d = 1; d < 256; d <<= 1) {
        int t = lds[tid];
        int u = (tid >= d) ? lds[tid - d] : 0;
        __syncthreads();
        lds[tid] = t + u;
        __syncthreads();
    }
    int excl = lds[tid] - tsum;  // exclusive prefix of this thread's chunk
    if (base + 0 < N_NODES) off[base + 0] = excl;
    if (base + 1 < N_NODES) off[base + 1] = excl + s1;
    if (base + 2 < N_NODES) off[base + 2] = excl + s2;
    if (base + 3 < N_NODES) off[base + 3] = excl + s3;
    if (tid == 255) bsum[blockIdx.x] = lds[255];
}

// scan2: single block, exclusive scan of nb block sums (nb <= 256)
__global__ void scan2_kernel(const int* __restrict__ bsum, int* __restrict__ boff, int nb) {
    __shared__ int lds[256];
    int tid = threadIdx.x;
    int v = (tid < nb) ? bsum[tid] : 0;
    lds[tid] = v;
    __syncthreads();
    for (int d = 1; d < 256; d <<= 1) {
        int t = lds[tid];
        int u = (tid >= d) ? lds[tid - d] : 0;
        __syncthreads();
        lds[tid] = t + u;
        __syncthreads();
    }
    if (tid < nb) boff[tid] = lds[tid] - v;
}

__global__ void scan3_kernel(int* __restrict__ off, const int* __restrict__ boff) {
    int i = blockIdx.x * blockDim.x + threadIdx.x;
    if (i < N_NODES) off[i] += boff[i / SCAN_B];
}

// scatter: place src id + dist into dst-sorted order (no atomics; uses rank)
__global__ void scatter_kernel(const int* __restrict__ ei,
                               const float* __restrict__ pos,
                               const int* __restrict__ off,
                               const int* __restrict__ rank,
                               int* __restrict__ src_s,
                               float* __restrict__ dist_s) {
    int e = blockIdx.x * blockDim.x + threadIdx.x;
    if (e >= N_EDGES) return;
    int s = ei[e];
    int d = ei[N_EDGES + e];
    float dx = pos[d * 3 + 0] - pos[s * 3 + 0];
    float dy = pos[d * 3 + 1] - pos[s * 3 + 1];
    float dz = pos[d * 3 + 2] - pos[s * 3 + 2];
    int t = off[d] + rank[e];
    src_s[t] = s;
    dist_s[t] = sqrtf(dx * dx + dy * dy + dz * dz);
}

// ------------------------------- model kernels ------------------------------
__global__ void encoder_kernel(const float* __restrict__ feat,
                               const float* __restrict__ w1, const float* __restrict__ b1,
                               const float* __restrict__ w2, const float* __restrict__ b2,
                               float* __restrict__ xout) {
    int n = blockIdx.x * blockDim.x + threadIdx.x;
    if (n >= N_NODES) return;
    float f[NODE_DIM];
    const float4* fp = reinterpret_cast<const float4*>(feat + (size_t)n * NODE_DIM);
#pragma unroll
    for (int k = 0; k < NODE_DIM / 4; ++k) {
        float4 v = fp[k];
        f[4 * k + 0] = v.x; f[4 * k + 1] = v.y;
        f[4 * k + 2] = v.z; f[4 * k + 3] = v.w;
    }
    float y[HID];
    mlp2<NODE_DIM>(f, w1, b1, w2, b2, y);
    store_row32(xout + (size_t)n * HID, y);
}

// per-layer node projections: p = x @ W1[0:32]  + b1   (dst half)
//                             q = x @ W1[32:64]        (src half)
__global__ void proj_kernel(const float* __restrict__ x,
                            const float* __restrict__ w1, const float* __restrict__ b1,
                            float* __restrict__ p, float* __restrict__ q) {
    int n = blockIdx.x * blockDim.x + threadIdx.x;
    if (n >= N_NODES) return;
    float xi[HID];
    load_row32(x + (size_t)n * HID, xi);
    float pp[HID], qq[HID];
#pragma unroll
    for (int j = 0; j < HID; ++j) { pp[j] = b1[j]; qq[j] = 0.0f; }
    for (int k = 0; k < HID; ++k) {
        float v = xi[k];
#pragma unroll
        for (int j = 0; j < HID; ++j) pp[j] = fmaf(v, w1[k * HID + j], pp[j]);
    }
    for (int k = 0; k < HID; ++k) {
        float v = xi[k];
#pragma unroll
        for (int j = 0; j < HID; ++j) qq[j] = fmaf(v, w1[(HID + k) * HID + j], qq[j]);
    }
    store_row32(p + (size_t)n * HID, pp);
    store_row32(q + (size_t)n * HID, qq);
}

// fused: per-node CSR gather + relu-accum + (@W2 + deg*b2) + update MLP, in-place x
__global__ void gather_update_kernel(float* __restrict__ x,
                                     const float* __restrict__ p,
                                     const float* __restrict__ q,
                                     const int* __restrict__ src_s,
                                     const float* __restrict__ dist_s,
                                     const int* __restrict__ off,
                                     const float* __restrict__ w1,   // for dist row (row 64)
                                     const float* __restrict__ w2,
                                     const float* __restrict__ b2,
                                     const float* __restrict__ uw1, const float* __restrict__ ub1,
                                     const float* __restrict__ uw2, const float* __restrict__ ub2) {
    int n = blockIdx.x * blockDim.x + threadIdx.x;
    if (n >= N_NODES) return;
    int t0 = off[n];
    int t1 = (n == N_NODES - 1) ? N_EDGES : off[n + 1];

    float pp[HID];
    load_row32(p + (size_t)n * HID, pp);
    float rsum[HID];
#pragma unroll
    for (int j = 0; j < HID; ++j) rsum[j] = 0.0f;

    const float* __restrict__ wd = w1 + 2 * HID * HID;  // dist row (uniform -> SGPR)
    for (int t = t0; t < t1; ++t) {
        int s = src_s[t];
        float dt = dist_s[t];
        float qq[HID];
        load_row32(q + (size_t)s * HID, qq);
#pragma unroll
        for (int j = 0; j < HID; ++j) {
            float h = fmaf(dt, wd[j], pp[j] + qq[j]);
            rsum[j] += fmaxf(h, 0.0f);
        }
    }

    float deg = (float)(t1 - t0);
    float in[2 * HID];
    load_row32(x + (size_t)n * HID, in);
#pragma unroll
    for (int j = 0; j < HID; ++j) in[HID + j] = b2[j] * deg;
    for (int k = 0; k < HID; ++k) {
        float v = rsum[k];
#pragma unroll
        for (int j = 0; j < HID; ++j) in[HID + j] = fmaf(v, w2[k * HID + j], in[HID + j]);
    }
    float y[HID];
    mlp2<2 * HID>(in, uw1, ub1, uw2, ub2, y);
    store_row32(x + (size_t)n * HID, y);
}

__global__ void out_kernel(const float* __restrict__ x,
                           const float* __restrict__ w, const float* __restrict__ b,
                           float* __restrict__ out) {
    int n = blockIdx.x * blockDim.x + threadIdx.x;
    if (n >= N_NODES) return;
    float in[HID];
    load_row32(x + (size_t)n * HID, in);
    float y[HID];
#pragma unroll
    for (int j = 0; j < HID; ++j) y[j] = b[j];
    for (int k = 0; k < HID; ++k) {
        float v = in[k];
#pragma unroll
        for (int j = 0; j < HID; ++j) y[j] = fmaf(v, w[k * HID + j], y[j]);
    }
    store_row32(out + (size_t)n * HID, y);
}

// ---------------------------------------------------------------------------
extern "C" void kernel_launch(void* const* d_in, const int* in_sizes, int n_in,
                              void* d_out, int out_size, void* d_ws, size_t ws_size,
                              hipStream_t stream) {
    const float* node_feat = (const float*)d_in[0];
    const float* pos       = (const float*)d_in[1];
    const int*   ei        = (const int*)  d_in[2];   // int32 on device
    const float* enc_w1    = (const float*)d_in[3];
    const float* enc_b1    = (const float*)d_in[4];
    const float* enc_w2    = (const float*)d_in[5];
    const float* enc_b2    = (const float*)d_in[6];
    const float* msg_w1    = (const float*)d_in[7];   // [3, 65, 32]
    const float* msg_b1    = (const float*)d_in[8];
    const float* msg_w2    = (const float*)d_in[9];   // [3, 32, 32]
    const float* msg_b2    = (const float*)d_in[10];
    const float* upd_w1    = (const float*)d_in[11];  // [3, 64, 32]
    const float* upd_b1    = (const float*)d_in[12];
    const float* upd_w2    = (const float*)d_in[13];
    const float* upd_b2    = (const float*)d_in[14];
    const float* out_w     = (const float*)d_in[15];
    const float* out_b     = (const float*)d_in[16];
    float* out = (float*)d_out;

    // workspace layout (4-byte elements), ~58.6 MB total
    char* ws = (char*)d_ws;
    float* x      = (float*)ws;                                   // N*32
    float* p      = x + (size_t)N_NODES * HID;                    // N*32
    float* q      = p + (size_t)N_NODES * HID;                    // N*32
    float* dist_s = q + (size_t)N_NODES * HID;                    // E
    int*   src_s  = (int*)(dist_s + (size_t)N_EDGES);             // E
    int*   rank   = src_s + (size_t)N_EDGES;                      // E
    int*   cnt    = rank + (size_t)N_EDGES;                       // N
    int*   off    = cnt + N_NODES;                                // N+1 (off[N] unused)
    int*   bsum   = off + (N_NODES + 1);                          // <=256
    int*   boff   = bsum + 256;                                   // <=256

    const int B = 256;
    const int gridE = (N_EDGES + B - 1) / B;
    const int gridN = (N_NODES + B - 1) / B;
    const int NB = (N_NODES + SCAN_B - 1) / SCAN_B;               // 98

    // ---- build CSR (once per launch) ----
    zero_int_kernel<<<(N_NODES + B - 1) / B, B, 0, stream>>>(cnt, N_NODES);
    rank_kernel<<<gridE, B, 0, stream>>>(ei, cnt, rank);
    scan1_kernel<<<NB, 256, 0, stream>>>(cnt, off, bsum);
    scan2_kernel<<<1, 256, 0, stream>>>(bsum, boff, NB);
    scan3_kernel<<<gridN, B, 0, stream>>>(off, boff);
    scatter_kernel<<<gridE, B, 0, stream>>>(ei, pos, off, rank, src_s, dist_s);

    // ---- model ----
    encoder_kernel<<<gridN, B, 0, stream>>>(node_feat, enc_w1, enc_b1, enc_w2, enc_b2, x);

    for (int l = 0; l < NUM_LAYERS; ++l) {
        const float* w1 = msg_w1 + (size_t)l * (2 * HID + 1) * HID;
        proj_kernel<<<gridN, B, 0, stream>>>(x, w1, msg_b1 + (size_t)l * HID, p, q);
        gather_update_kernel<<<gridN, B, 0, stream>>>(
            x, p, q, src_s, dist_s, off,
            w1,
            msg_w2 + (size_t)l * HID * HID,
            msg_b2 + (size_t)l * HID,
            upd_w1 + (size_t)l * (2 * HID) * HID,
            upd_b1 + (size_t)l * HID,
            upd_w2 + (size_t)l * HID * HID,
            upd_b2 + (size_t)l * HID);
    }
    out_kernel<<<gridN, B, 0, stream>>>(x, out_w, out_b, out);
}